// Round 3
// baseline (247.556 us; speedup 1.0000x reference)
//
#include <hip/hip_runtime.h>
#include <hip/hip_bf16.h>
#include <math.h>

// Problem constants (B,C,D,H,W) = (2,64,32,64,96), qk=32
constexpr int Cc = 64, Dd = 32, Hh = 64, Ww = 96, QKd = 32;
constexpr int CSTRIDE = Dd * Hh * Ww;   // 196608
constexpr int BDIM = 256;               // 4 waves

// ln(10000)/32 and ln(10000)/64
#define FREQ_QK 0.28782313662425574f
#define FREQ_V  0.14391156831212787f

typedef __bf16 bf16_t;
typedef bf16_t bf16x8 __attribute__((ext_vector_type(8)));
typedef bf16_t bf16x4 __attribute__((ext_vector_type(4)));
typedef float  floatx4 __attribute__((ext_vector_type(4)));

// LDS (bf16 elements), 40960 B total -> 4 blocks/CU (160 KB exactly).
//  Qs [96 w][40] : Q^T, A-operand for S. stride 40 el = 20 words mod 32 -> b128 frags conflict-free
//  Ks [96 w][40] : K^T, B-operand for S.
//  Vs [64 c][100]: V, A-operand for PV. stride 100 el = 50 words == 18 mod 32 -> b64 frags conflict-free
//  Ps 4 x [16 i][100]: per-WAVE P slice (B-operand for PV) -- wave-private, no barrier needed
constexpr int QS_STRIDE = 40;
constexpr int VS_STRIDE = 100;
constexpr int PS_STRIDE = 100;
constexpr int OFF_KS = 96 * QS_STRIDE;            // 3840
constexpr int OFF_VS = 2 * 96 * QS_STRIDE;        // 7680
constexpr int OFF_PS = OFF_VS + 64 * VS_STRIDE;   // 14080
constexpr int PS_WAVE = 16 * PS_STRIDE;           // 1600
constexpr int SMEM_ELEMS = OFF_PS + 4 * PS_WAVE;  // 20480 el = 40960 B

__device__ inline bf16x8 ld_frag64(const bf16_t* p) {
    bf16x4 lo = *(const bf16x4*)p;
    bf16x4 hi = *(const bf16x4*)(p + 4);
    bf16x8 f;
    f[0] = lo[0]; f[1] = lo[1]; f[2] = lo[2]; f[3] = lo[3];
    f[4] = hi[0]; f[5] = hi[1]; f[6] = hi[2]; f[7] = hi[3];
    return f;
}

__global__ __launch_bounds__(BDIM, 4)
void row_attn_v3(const float* __restrict__ x,
                 const float* __restrict__ Wq, const float* __restrict__ bq,
                 const float* __restrict__ Wk, const float* __restrict__ bk,
                 const float* __restrict__ Wv, const float* __restrict__ bv,
                 const float* __restrict__ gamma,
                 float* __restrict__ y)
{
    __shared__ __align__(16) bf16_t smem[SMEM_ELEMS];
    bf16_t* Qs = smem;
    bf16_t* Ks = smem + OFF_KS;
    bf16_t* Vs = smem + OFF_VS;

    const int t    = threadIdx.x;
    const int lane = t & 63;
    const int wid  = t >> 6;       // wave id 0..3
    const int l16  = lane & 15;
    const int quad = lane >> 4;    // 0..3
    bf16_t* Psw = smem + OFF_PS + wid * PS_WAVE;   // this wave's private P slice

    const int bid = blockIdx.x;
    const int b   = bid / (Dd * Hh);
    const int rem = bid % (Dd * Hh);
    const int d   = rem / Hh;
    const int h   = rem % Hh;
    const int base0 = b * (Cc * CSTRIDE) + d * (Hh * Ww) + h * Ww;
    const float* xblk = x + base0;

    // ---- per-wave weight A-fragments: wave0=Q, wave1=K, waves2/3=V halves ----
    const float* Wmat = (wid == 0) ? Wq : (wid == 1) ? Wk : Wv;
    const float* bias = (wid == 0) ? bq : (wid == 1) ? bk : bv;
    const float freqc = (wid < 2) ? FREQ_QK : FREQ_V;
    const int   mbase = (wid == 3) ? 32 : 0;

    bf16x8 wfrag[2][2];
#pragma unroll
    for (int mt = 0; mt < 2; ++mt)
#pragma unroll
        for (int kt = 0; kt < 2; ++kt) {
            const float* p = Wmat + (mbase + mt * 16 + l16) * 64 + kt * 32 + quad * 8;
            float4 lo = *(const float4*)p;
            float4 hi = *(const float4*)(p + 4);
            bf16x8 f;
            f[0] = (bf16_t)lo.x; f[1] = (bf16_t)lo.y; f[2] = (bf16_t)lo.z; f[3] = (bf16_t)lo.w;
            f[4] = (bf16_t)hi.x; f[5] = (bf16_t)hi.y; f[6] = (bf16_t)hi.z; f[7] = (bf16_t)hi.w;
            wfrag[mt][kt] = f;
        }
    float biasv[2][4], freq2[2][2];
#pragma unroll
    for (int mt = 0; mt < 2; ++mt) {
#pragma unroll
        for (int r = 0; r < 4; ++r)
            biasv[mt][r] = bias[mbase + mt * 16 + quad * 4 + r];
#pragma unroll
        for (int p2 = 0; p2 < 2; ++p2)
            freq2[mt][p2] = __expf(-(float)(mbase + mt * 16 + quad * 4 + 2 * p2) * freqc);
    }

    // ---- projections (B-frags of X straight from global; L1-shared across waves) ----
    // D layout: col(n=w)=l16, row(m)=quad*4+r. Bias + sinusoidal PE fused.
    bf16_t* dstQK = (wid == 0) ? Qs : Ks;
#pragma unroll
    for (int nt = 0; nt < 6; ++nt) {
        bf16x8 bfr[2];
#pragma unroll
        for (int kt = 0; kt < 2; ++kt) {
#pragma unroll
            for (int j = 0; j < 8; ++j) {
                int c = kt * 32 + quad * 8 + j;
                bfr[kt][j] = (bf16_t)xblk[c * CSTRIDE + nt * 16 + l16];
            }
        }
#pragma unroll
        for (int mt = 0; mt < 2; ++mt) {
            floatx4 acc = {0.f, 0.f, 0.f, 0.f};
            acc = __builtin_amdgcn_mfma_f32_16x16x32_bf16(wfrag[mt][0], bfr[0], acc, 0, 0, 0);
            acc = __builtin_amdgcn_mfma_f32_16x16x32_bf16(wfrag[mt][1], bfr[1], acc, 0, 0, 0);
            float wv = (float)(nt * 16 + l16);
            float out[4];
#pragma unroll
            for (int p2 = 0; p2 < 2; ++p2) {
                float sn, cs;
                __sincosf(wv * freq2[mt][p2], &sn, &cs);
                out[2 * p2]     = acc[2 * p2]     + biasv[mt][2 * p2]     + sn;
                out[2 * p2 + 1] = acc[2 * p2 + 1] + biasv[mt][2 * p2 + 1] + cs;
            }
            if (wid < 2) {
                // Q^T/K^T layout: row w, 4 consecutive q -> one b64 write
                bf16x4 pk;
                pk[0] = (bf16_t)out[0]; pk[1] = (bf16_t)out[1];
                pk[2] = (bf16_t)out[2]; pk[3] = (bf16_t)out[3];
                *(bf16x4*)(&dstQK[(nt * 16 + l16) * QS_STRIDE + mt * 16 + quad * 4]) = pk;
            } else {
                // V layout [c][j]
#pragma unroll
                for (int r = 0; r < 4; ++r)
                    Vs[(mbase + mt * 16 + quad * 4 + r) * VS_STRIDE + nt * 16 + l16] = (bf16_t)out[r];
            }
        }
    }
    __syncthreads();   // the ONLY barrier: Q/K/V visible to all waves

    // ---- per-wave: S i-tile -> register softmax -> private P slice -> PV -> epilogue ----
    const float g = gamma[0];
    const int it0 = (wid < 2) ? wid * 2 : wid + 2;   // i-tiles {0,1},{2,3},{4},{5}
    const int itc = (wid < 2) ? 2 : 1;

    for (int ii = 0; ii < itc; ++ii) {
        const int it = it0 + ii;

        // S = Q^T K, K-dim = 32 (one MFMA per 16x16 tile)
        bf16x8 afr = *(const bf16x8*)(&Qs[(it * 16 + l16) * QS_STRIDE + quad * 8]);
        floatx4 sacc[6];
#pragma unroll
        for (int jt = 0; jt < 6; ++jt) {
            bf16x8 bfr = *(const bf16x8*)(&Ks[(jt * 16 + l16) * QS_STRIDE + quad * 8]);
            floatx4 z = {0.f, 0.f, 0.f, 0.f};
            sacc[jt] = __builtin_amdgcn_mfma_f32_16x16x32_bf16(afr, bfr, z, 0, 0, 0);
        }
        // softmax per row (row i = it*16 + quad*4 + r lives across 16 lanes x 6 regs)
#pragma unroll
        for (int r = 0; r < 4; ++r) {
            float m = sacc[0][r];
#pragma unroll
            for (int jt = 1; jt < 6; ++jt) m = fmaxf(m, sacc[jt][r]);
#pragma unroll
            for (int msk = 1; msk < 16; msk <<= 1) m = fmaxf(m, __shfl_xor(m, msk));
            float e[6], sum = 0.f;
#pragma unroll
            for (int jt = 0; jt < 6; ++jt) { e[jt] = __expf(sacc[jt][r] - m); sum += e[jt]; }
#pragma unroll
            for (int msk = 1; msk < 16; msk <<= 1) sum += __shfl_xor(sum, msk);
            float inv = 1.0f / sum;
#pragma unroll
            for (int jt = 0; jt < 6; ++jt)
                Psw[(quad * 4 + r) * PS_STRIDE + jt * 16 + l16] = (bf16_t)(e[jt] * inv);
        }

        // PV: O[c][i-tile] = V @ P^T  (wave-private P -> no barrier, lgkmcnt only)
        bf16x8 pfr[3];
#pragma unroll
        for (int ks = 0; ks < 3; ++ks)
            pfr[ks] = ld_frag64(&Psw[l16 * PS_STRIDE + ks * 32 + quad * 8]);
#pragma unroll
        for (int ct = 0; ct < 4; ++ct) {
            floatx4 oacc = {0.f, 0.f, 0.f, 0.f};
#pragma unroll
            for (int ks = 0; ks < 3; ++ks) {
                bf16x8 vfr = ld_frag64(&Vs[(ct * 16 + l16) * VS_STRIDE + ks * 32 + quad * 8]);
                oacc = __builtin_amdgcn_mfma_f32_16x16x32_bf16(vfr, pfr[ks], oacc, 0, 0, 0);
            }
#pragma unroll
            for (int r = 0; r < 4; ++r) {
                int c  = ct * 16 + quad * 4 + r;
                int gi = base0 + c * CSTRIDE + it * 16 + l16;
                y[gi] = fmaf(g, oacc[r], x[gi]);   // exact fp32 residual
            }
        }
    }
}

extern "C" void kernel_launch(void* const* d_in, const int* in_sizes, int n_in,
                              void* d_out, int out_size, void* d_ws, size_t ws_size,
                              hipStream_t stream) {
    const float* x     = (const float*)d_in[0];
    const float* Wq    = (const float*)d_in[1];
    const float* bq    = (const float*)d_in[2];
    const float* Wk    = (const float*)d_in[3];
    const float* bk    = (const float*)d_in[4];
    const float* Wv    = (const float*)d_in[5];
    const float* bv    = (const float*)d_in[6];
    const float* gamma = (const float*)d_in[7];
    float* y = (float*)d_out;

    dim3 grid(2 * 32 * 64);   // one block per (b,d,h)
    row_attn_v3<<<grid, BDIM, 0, stream>>>(x, Wq, bq, Wk, bk, Wv, bv, gamma, y);
}